// Round 14
// baseline (168.465 us; speedup 1.0000x reference)
//
#include <hip/hip_runtime.h>
#include <hip/hip_bf16.h>
#include <math.h>

#define B_ 2
#define N_ 2048
#define C_ 1024
#define H_ 16
#define G_ 4
#define D_ 64
#define QKV_N 1152   // 1024 q + 64 ksum + 64 vsum

#define QSCALE 0.18033688011112042f   // 0.125 * log2(e)

using short8  = __attribute__((ext_vector_type(8))) short;
using short4v = __attribute__((ext_vector_type(4))) short;
using float4v = __attribute__((ext_vector_type(4))) float;

#if __has_builtin(__builtin_amdgcn_mfma_f32_16x16x16_bf16)
#define MFMA16K16(A, B, C) __builtin_amdgcn_mfma_f32_16x16x16_bf16(A, B, C, 0, 0, 0)
#else
#define MFMA16K16(A, B, C) __builtin_amdgcn_mfma_f32_16x16x16bf16_1k(A, B, C, 0, 0, 0)
#endif

__device__ __forceinline__ ushort f2bf(float f) {
    union { float f; unsigned u; } v; v.f = f;
    unsigned r = (v.u + 0x7FFF + ((v.u >> 16) & 1)) >> 16;  // RNE
    return (ushort)r;
}
__device__ __forceinline__ float bf2f(ushort u) {
    union { unsigned u; float f; } t; t.u = ((unsigned)u) << 16; return t.f;
}
__device__ __forceinline__ unsigned pack_bf16(float a, float b) {
#if __has_builtin(__builtin_amdgcn_cvt_pk_bf16_f32)
    auto t = __builtin_amdgcn_cvt_pk_bf16_f32(a, b);
    unsigned r; __builtin_memcpy(&r, &t, 4); return r;
#else
    return (unsigned)f2bf(a) | ((unsigned)f2bf(b) << 16);
#endif
}
__device__ __forceinline__ float fexp2(float x) {
#if __has_builtin(__builtin_amdgcn_exp2f)
    return __builtin_amdgcn_exp2f(x);
#else
    return exp2f(x);
#endif
}

// ---------------------------------------------------------------------------
// Fused prep (one launch):
//   blocks [0,4096)     : x fp32 -> bf16
//   [4096,4352)         : w_q^T   -> wqkvT rows 0..1023
//   [4352,4608)         : w_out^T -> woutT
//   [4608,4624)         : kv weight g-sum + transpose -> wqkvT rows 1024..1151
// ---------------------------------------------------------------------------
__device__ void tconv_body(const float* __restrict__ src, ushort* __restrict__ dst,
                           int K, int N, int bx, int by, float (*T)[65]) {
    const int n0 = bx * 64, k0 = by * 64;
    const int tid = threadIdx.x;
    #pragma unroll
    for (int s = 0; s < 16; ++s) {
        int idx = tid + s * 256; int r = idx >> 6, cc = idx & 63;
        T[r][cc] = src[(size_t)(k0 + r) * N + n0 + cc];
    }
    __syncthreads();
    #pragma unroll
    for (int s = 0; s < 16; ++s) {
        int idx = tid + s * 256; int r = idx >> 6, cc = idx & 63;
        dst[(size_t)(n0 + r) * K + k0 + cc] = f2bf(T[cc][r]);
    }
}

__global__ void prep(const float* __restrict__ x, const float* __restrict__ w_q,
                     const float* __restrict__ w_kv, const float* __restrict__ w_out,
                     ushort* __restrict__ xb, ushort* __restrict__ wqkvT,
                     ushort* __restrict__ woutT) {
    __shared__ float T[64][65];
    const int blk = blockIdx.x, tid = threadIdx.x;
    if (blk < 4096) {
        int i = blk * 1024 + tid * 4;
        float4 v = *(const float4*)(x + i);
        ushort4 o;
        o.x = f2bf(v.x); o.y = f2bf(v.y); o.z = f2bf(v.z); o.w = f2bf(v.w);
        *(ushort4*)(xb + i) = o;
    } else if (blk < 4352) {
        int idx = blk - 4096;
        tconv_body(w_q, wqkvT, C_, C_, idx & 15, idx >> 4, T);
    } else if (blk < 4608) {
        int idx = blk - 4352;
        tconv_body(w_out, woutT, C_, C_, idx & 15, idx >> 4, T);
    } else {
        // kv g-sum + transpose: wqkvT[1024+d][k] = sum_g w_kv[k][g*64+d],
        //                       wqkvT[1088+d][k] = sum_g w_kv[k][256+g*64+d]
        const int k0 = (blk - 4608) * 64;
        #pragma unroll
        for (int it = 0; it < 4; ++it) {
            int p = tid + it * 256;              // 1024 (kk, d-quad) pairs
            int kk = p >> 4, d4 = (p & 15) * 4;
            float ks[4] = {0, 0, 0, 0}, vs[4] = {0, 0, 0, 0};
            #pragma unroll
            for (int g = 0; g < G_; ++g) {
                float4 a = *(const float4*)(w_kv + (size_t)(k0 + kk) * 512 + g * 64 + d4);
                float4 b = *(const float4*)(w_kv + (size_t)(k0 + kk) * 512 + 256 + g * 64 + d4);
                ks[0] += a.x; ks[1] += a.y; ks[2] += a.z; ks[3] += a.w;
                vs[0] += b.x; vs[1] += b.y; vs[2] += b.z; vs[3] += b.w;
            }
            #pragma unroll
            for (int e = 0; e < 4; ++e) {
                wqkvT[(size_t)(1024 + d4 + e) * C_ + k0 + kk] = f2bf(ks[e]);
                wqkvT[(size_t)(1088 + d4 + e) * C_ + k0 + kk] = f2bf(vs[e]);
            }
        }
    }
}

// ---------------------------------------------------------------------------
// bf16 MFMA GEMM, 128x64 tile, BK=64, double-buffered LDS, counted-vmcnt
// pipeline (T4, R12), T1 XCD remap (R11), global-side XOR chunk swizzle,
// 4 waves x acc[2][4].  [R12 config — best measured total 168.8]
// MODE 1 (qkv): bx<16  -> fused rope+QSCALE on Q  -> qkvb.
//               bx==16 -> fused rope on Ksum      -> Kt[row][d].
//               bx==17 -> Vsum transpose          -> VtT[d][row].
// MODE 2 (out): f32 C write.
// ---------------------------------------------------------------------------
template <int MODE>
__global__ __launch_bounds__(256) void gemm128p(const ushort* __restrict__ A,
                                                const ushort* __restrict__ Bt,
                                                void* __restrict__ Cv,
                                                ushort* __restrict__ Kt,
                                                ushort* __restrict__ VtT,
                                                int M, int N, int K) {
    __shared__ __align__(16) ushort As[2][128 * 64];
    __shared__ __align__(16) ushort Bs[2][64 * 64];

    const int tid = threadIdx.x, wave = tid >> 6, lane = tid & 63;
    const int g = lane >> 4, c = lane & 15;

    // XCD-locality remap (T1, R11): by-chunks of 4 per XCD
    const int L = blockIdx.x;
    const int xcd = L & 7, local = L >> 3;
    const int by = xcd * 4 + (local & 3);
    const int bx = local >> 2;
    const int m0 = by * 128, n0 = bx * 64;

    const int lr = tid >> 3;                 // row within 32-row slab
    const int lq = tid & 7;                  // 16B-chunk slot within row
    const int gsw = (lq ^ (lr & 7)) * 8;     // global-side XOR chunk swizzle
    const ushort* pa = A  + (size_t)(m0 + lr) * K + gsw;
    const ushort* pb = Bt + (size_t)(n0 + lr) * K + gsw;

    auto stage = [&](int buf, int k0) {
        #pragma unroll
        for (int i = 0; i < 4; ++i)
            __builtin_amdgcn_global_load_lds(
                (const __attribute__((address_space(1))) void*)(pa + (size_t)i * 32 * K + k0),
                (__attribute__((address_space(3))) void*)&As[buf][(i * 32 + wave * 8) * 64], 16, 0, 0);
        #pragma unroll
        for (int i = 0; i < 2; ++i)
            __builtin_amdgcn_global_load_lds(
                (const __attribute__((address_space(1))) void*)(pb + (size_t)i * 32 * K + k0),
                (__attribute__((address_space(3))) void*)&Bs[buf][(i * 32 + wave * 8) * 64], 16, 0, 0);
    };

    float4v acc[2][4];
    #pragma unroll
    for (int m = 0; m < 2; ++m)
        #pragma unroll
        for (int n = 0; n < 4; ++n) acc[m][n] = {0, 0, 0, 0};

    const int NT = K >> 6;                   // 16 for K=1024
    stage(0, 0);
    stage(1, 64);                            // 12 loads in flight

    for (int t = 0; t < NT; ++t) {
        if (t + 1 < NT) {
            asm volatile("s_waitcnt vmcnt(6)" ::: "memory");   // own tile-t loads done
        } else {
            asm volatile("s_waitcnt vmcnt(0)" ::: "memory");   // final tile: drain
        }
        __builtin_amdgcn_s_barrier();        // all waves staged tile t

        const int cur = t & 1;
        #pragma unroll
        for (int kk = 0; kk < 2; ++kk) {
            const int c7 = c & 7;
            short8 af[2], bf[4];
            #pragma unroll
            for (int m = 0; m < 2; ++m)
                af[m] = *(const short8*)&As[cur][(wave * 32 + m * 16 + c) * 64 + ((kk * 4 + g) ^ c7) * 8];
            #pragma unroll
            for (int n = 0; n < 4; ++n)
                bf[n] = *(const short8*)&Bs[cur][(n * 16 + c) * 64 + ((kk * 4 + g) ^ c7) * 8];
            #pragma unroll
            for (int m = 0; m < 2; ++m)
                #pragma unroll
                for (int n = 0; n < 4; ++n)
                    acc[m][n] = __builtin_amdgcn_mfma_f32_16x16x32_bf16(af[m], bf[n], acc[m][n], 0, 0, 0);
        }

        __builtin_amdgcn_s_barrier();        // all waves done reading buf cur
        if (t + 2 < NT) stage(cur, (t + 2) << 6);   // restage freed buffer
    }

    if (MODE == 1) {
        if (bx < 16) {
            // fused rope + QSCALE on Q: qkvb[rowi][bx*64 + d], d = nn*16+c
            const float invf_e = __powf(10000.0f, -(float)c * (1.0f / 32.0f));
            const float invf_o = __powf(10000.0f, -(float)(c + 16) * (1.0f / 32.0f));
            #pragma unroll
            for (int m = 0; m < 2; ++m)
                #pragma unroll
                for (int r = 0; r < 4; ++r) {
                    const int rowi = m0 + wave * 32 + m * 16 + 4 * g + r;
                    const float nf = (float)(rowi & (N_ - 1));
                    float sn0, cs0, sn1, cs1;
                    __sincosf(nf * invf_e, &sn0, &cs0);
                    __sincosf(nf * invf_o, &sn1, &cs1);
                    #pragma unroll
                    for (int nn = 0; nn < 4; ++nn) {
                        const float v = acc[m][nn][r], p = acc[m][nn ^ 2][r];
                        const float rh = (nn < 2) ? -p : p;
                        const float sn = (nn & 1) ? sn1 : sn0;
                        const float cs = (nn & 1) ? cs1 : cs0;
                        ((ushort*)Cv)[(size_t)rowi * N + n0 + nn * 16 + c] =
                            f2bf((v * cs + rh * sn) * QSCALE);
                    }
                }
            return;
        }
        if (bx == 16) {
            // fused rope on Ksum: Kt[rowi][d] = k*cos + rot_half(k)*sin
            const float invf_e = __powf(10000.0f, -(float)c * (1.0f / 32.0f));
            const float invf_o = __powf(10000.0f, -(float)(c + 16) * (1.0f / 32.0f));
            #pragma unroll
            for (int m = 0; m < 2; ++m)
                #pragma unroll
                for (int r = 0; r < 4; ++r) {
                    const int rowi = m0 + wave * 32 + m * 16 + 4 * g + r;
                    const float nf = (float)(rowi & (N_ - 1));
                    float sn0, cs0, sn1, cs1;
                    __sincosf(nf * invf_e, &sn0, &cs0);
                    __sincosf(nf * invf_o, &sn1, &cs1);
                    #pragma unroll
                    for (int nn = 0; nn < 4; ++nn) {
                        const float v = acc[m][nn][r], p = acc[m][nn ^ 2][r];
                        const float rh = (nn < 2) ? -p : p;
                        const float sn = (nn & 1) ? sn1 : sn0;
                        const float cs = (nn & 1) ? cs1 : cs0;
                        Kt[(size_t)rowi * 64 + nn * 16 + c] = f2bf(v * cs + rh * sn);
                    }
                }
        } else {
            // Vsum transpose: VtT[b][d][n]
            #pragma unroll
            for (int m = 0; m < 2; ++m)
                #pragma unroll
                for (int nn = 0; nn < 4; ++nn)
                    #pragma unroll
                    for (int r = 0; r < 4; ++r) {
                        const int rowi = m0 + wave * 32 + m * 16 + 4 * g + r;
                        const int n = rowi & (N_ - 1), bb = rowi >> 11;
                        VtT[((size_t)bb * 64 + nn * 16 + c) * N_ + n] = f2bf(acc[m][nn][r]);
                    }
        }
        return;
    }

    #pragma unroll
    for (int m = 0; m < 2; ++m)
        #pragma unroll
        for (int n = 0; n < 4; ++n)
            #pragma unroll
            for (int r = 0; r < 4; ++r) {
                int rowi = m0 + wave * 32 + m * 16 + 4 * g + r;
                int coli = n0 + n * 16 + c;
                ((float*)Cv)[(size_t)rowi * N + coli] = acc[m][n][r];
            }
}

// ---------------------------------------------------------------------------
// Flash attention v17: SINGLE-PASS (no K-split, no combine kernel).
// [R10/R12-proven: 59.9-60.3 us, best attn. R13's single-barrier-dbuf +
// setprio bundle regressed to 65.4 (setprio on barrier-synced lockstep
// waves = m190's negative regime) -- reverted to this exact form.]
// ---------------------------------------------------------------------------
__global__ __launch_bounds__(512) void attn17(
        const ushort* __restrict__ qkvb, const ushort* __restrict__ Kt,
        const ushort* __restrict__ VtT, ushort* __restrict__ ao) {
    const int qt = blockIdx.x & 7;
    const int h  = (blockIdx.x >> 3) & 15;
    const int b  = blockIdx.x >> 7;
    const int tid = threadIdx.x, wave = tid >> 6, lane = tid & 63;
    const int g = lane >> 4, c = lane & 15;

    __shared__ __align__(16) ushort Ksh[64 * 64];   // [j-local][d], XOR-swizzled
    __shared__ __align__(16) ushort Vsh[64 * 64];   // [d][j-local], XOR-swizzled

    const int i0 = qt * 256 + wave * 32;

    short8 qf[2][2];
    #pragma unroll
    for (int a = 0; a < 2; ++a) {
        const int row = i0 + a * 16 + c;
        const ushort* qrow = qkvb + (size_t)(b * N_ + row) * QKV_N + h * 64;
        qf[a][0] = *(const short8*)(qrow + 8 * g);
        qf[a][1] = *(const short8*)(qrow + 32 + 8 * g);
    }

    float4v o[2][4];
    #pragma unroll
    for (int a = 0; a < 2; ++a)
        #pragma unroll
        for (int f = 0; f < 4; ++f) o[a][f] = {0, 0, 0, 0};
    float ll[2] = {0.f, 0.f};

    const ushort* Kb = Kt  + (size_t)b * N_ * 64;
    const ushort* Vb = VtT + (size_t)b * 64 * N_;
    const int lr8 = lane >> 3, lq8 = lane & 7;
    const int wpos = (lq8 ^ lr8) * 8;
    const int NT = N_ / 64;

    // each wave stages 8 rows of K ([j][d]) and 8 rows of V ([d][j])
    short8 kr0 = *(const short8*)(Kb + (size_t)(wave * 8 + lr8) * 64 + lq8 * 8);
    short8 vr0 = *(const short8*)(Vb + (size_t)(wave * 8 + lr8) * N_ + lq8 * 8);

    for (int t = 0; t < NT; ++t) {
        __syncthreads();
        *(short8*)&Ksh[(wave * 8 + lr8) * 64 + wpos] = kr0;
        *(short8*)&Vsh[(wave * 8 + lr8) * 64 + wpos] = vr0;
        __syncthreads();
        if (t + 1 < NT) {
            const int jn = (t + 1) * 64;
            kr0 = *(const short8*)(Kb + (size_t)(jn + wave * 8 + lr8) * 64 + lq8 * 8);
            vr0 = *(const short8*)(Vb + (size_t)(wave * 8 + lr8) * N_ + jn + lq8 * 8);
        }

        #pragma unroll
        for (int jt4 = 0; jt4 < 4; ++jt4) {
            const int R = jt4 * 16 + c;
            short8 kf0 = *(const short8*)&Ksh[R * 64 + ((g ^ (c & 7)) * 8)];
            short8 kf1 = *(const short8*)&Ksh[R * 64 + (((g ^ 4) ^ (c & 7)) * 8)];
            short4v vf[4];
            #pragma unroll
            for (int f = 0; f < 4; ++f)
                vf[f] = *(const short4v*)&Vsh[(16 * f + c) * 64 +
                          (((jt4 * 2 + (g >> 1)) ^ (c & 7)) * 8) + (g & 1) * 4];

            #pragma unroll
            for (int a = 0; a < 2; ++a) {
                float4v st = {0, 0, 0, 0};
                st = __builtin_amdgcn_mfma_f32_16x16x32_bf16(kf0, qf[a][0], st, 0, 0, 0);
                st = __builtin_amdgcn_mfma_f32_16x16x32_bf16(kf1, qf[a][1], st, 0, 0, 0);
                float p0 = fexp2(st[0]), p1 = fexp2(st[1]);
                float p2 = fexp2(st[2]), p3 = fexp2(st[3]);
                ll[a] += (p0 + p1) + (p2 + p3);
                union { unsigned u[2]; short4v v; } pk;
                pk.u[0] = pack_bf16(p0, p1);
                pk.u[1] = pack_bf16(p2, p3);
                #pragma unroll
                for (int f = 0; f < 4; ++f)
                    o[a][f] = MFMA16K16(vf[f], pk.v, o[a][f]);
            }
        }
    }

    #pragma unroll
    for (int a = 0; a < 2; ++a) {
        float lt = ll[a];
        lt += __shfl_xor(lt, 16, 64);
        lt += __shfl_xor(lt, 32, 64);
        const float inv = 1.0f / lt;
        const int row = i0 + a * 16 + c;
        #pragma unroll
        for (int f = 0; f < 4; ++f) {
            ushort4 w;
            w.x = f2bf(o[a][f][0] * inv); w.y = f2bf(o[a][f][1] * inv);
            w.z = f2bf(o[a][f][2] * inv); w.w = f2bf(o[a][f][3] * inv);
            *(ushort4*)(ao + (size_t)(b * N_ + row) * 1024 + h * 64 + 16 * f + 4 * g) = w;
        }
    }
}

// ---------------------------------------------------------------------------
extern "C" void kernel_launch(void* const* d_in, const int* in_sizes, int n_in,
                              void* d_out, int out_size, void* d_ws, size_t ws_size,
                              hipStream_t stream) {
    const float* x     = (const float*)d_in[0];
    const float* w_q   = (const float*)d_in[1];
    const float* w_kv  = (const float*)d_in[2];
    const float* w_out = (const float*)d_in[3];
    float* out = (float*)d_out;

    const int M = B_ * N_;                               // 4096
    ushort* xb    = (ushort*)d_ws;                       // 4096*1024  (-> ao)
    ushort* wqkvT = xb    + (size_t)M * C_;              // 1152*1024
    ushort* woutT = wqkvT + (size_t)QKV_N * C_;          // 1024*1024
    ushort* qkvb  = woutT + (size_t)C_ * C_;             // 4096*1152
    ushort* Kt    = qkvb  + (size_t)M * QKV_N;           // 2*2048*64
    ushort* VtT   = Kt    + (size_t)B_ * N_ * D_;        // 2*64*2048
    ushort* ao    = xb;   // xb dead after qkv GEMM; attn writes final here

    prep<<<4624, 256, 0, stream>>>(x, w_q, w_kv, w_out, xb, wqkvT, woutT);
    gemm128p<1><<<(QKV_N / 64) * (M / 128), 256, 0, stream>>>(xb, wqkvT, qkvb, Kt, VtT, M, QKV_N, C_);
    attn17<<<B_ * H_ * (N_ / 256), 512, 0, stream>>>(qkvb, Kt, VtT, ao);
    gemm128p<2><<<(C_ / 64) * (M / 128), 256, 0, stream>>>(ao, woutT, out, nullptr, nullptr, M, C_, C_);
}